// Round 6
// baseline (505.364 us; speedup 1.0000x reference)
//
#include <hip/hip_runtime.h>
#include <cstdint>
#include <cstddef>

// Sizes fixed by the problem.
#define BTOK 1024
#define DDIM 1024
#define EEXP 16
#define HDIM 2048
#define ODIM 1024

typedef __bf16 bh;
typedef bh bh8 __attribute__((ext_vector_type(8)));
typedef bh bh4 __attribute__((ext_vector_type(4)));
typedef float fx4 __attribute__((ext_vector_type(4)));

// ---------------- transpose+convert+tile: fp32 [e][K][N] -> staging-ready tiles ----------------
// Output tile (e, nt, kt) is TW*32 bh, contiguous; byte task*16 holds
// W[e][k0 + ((task&3)^(row&3))*8 + u][n0 + row], row = task>>2, u = 0..7 —
// the exact LDS image the GEMMs' COMPUTE expects when staged linearly.
// TW = panel width (64 or 128), TS = log2(TW/4).
__global__ __launch_bounds__(256) void k_tcvt2(const float* __restrict__ in,
                                               bh* __restrict__ out, int K, int N,
                                               int KT, int NT, int TW, int TS) {
  const int kt = blockIdx.x, nt = blockIdx.y, e = blockIdx.z;
  const int k0 = kt * 32, n0 = nt * TW;
  const float* pin = in + (size_t)e * K * N + (size_t)k0 * N + n0;
  bh* pout = out + (((size_t)e * NT + nt) * KT + kt) * (size_t)(TW * 32);
  __shared__ float t[32][129];
  const int tid = threadIdx.x;
  const int tw4 = TW >> 2;
  for (int idx = tid; idx < 32 * tw4; idx += 256) {
    int kk = idx >> TS, c4 = (idx & (tw4 - 1)) << 2;
    fx4 v = *(const fx4*)(pin + (size_t)kk * N + c4);
#pragma unroll
    for (int u = 0; u < 4; ++u) t[kk][c4 + u] = v[u];
  }
  __syncthreads();
  for (int task = tid; task < TW * 4; task += 256) {
    int row = task >> 2, s = task & 3, o = s ^ (row & 3);
    bh8 w;
#pragma unroll
    for (int u = 0; u < 8; ++u) w[u] = (bh)t[o * 8 + u][row];
    *(bh8*)(pout + (size_t)task * 8) = w;
  }
}

// ---------------- gating: one block per token ----------------
__global__ __launch_bounds__(256) void k_gating(
    const float* __restrict__ x, const float* __restrict__ wg,
    const float* __restrict__ wn, const float* __restrict__ nz,
    bh* __restrict__ xbf, unsigned* __restrict__ cnt,
    int* __restrict__ tok_buck, float* __restrict__ gate_buck,
    float* __restrict__ imp_part, float* __restrict__ load_part) {
  const int b = blockIdx.x, tid = threadIdx.x;
  __shared__ __align__(16) float xs[1024];
  __shared__ float part[32][9];
  __shared__ float vals[32];
  fx4 v = *(const fx4*)(x + (size_t)b * 1024 + tid * 4);
  *(fx4*)(xs + tid * 4) = v;
  bh4 xb;
#pragma unroll
  for (int u = 0; u < 4; ++u) xb[u] = (bh)v[u];
  *(bh4*)(xbf + (size_t)b * 1024 + tid * 4) = xb;
  __syncthreads();
  const int col = tid & 31, g = tid >> 5;
  const float* wp = ((col < 16) ? wg : wn) + (col & 15);
  float s = 0.f;
  for (int it = g * 128; it < g * 128 + 128; ++it) s += xs[it] * wp[it * 16];
  part[col][g] = s;
  __syncthreads();
  if (tid < 32) {
    float tsum = 0.f;
#pragma unroll
    for (int gg = 0; gg < 8; ++gg) tsum += part[tid][gg];
    vals[tid] = tsum;
  }
  __syncthreads();
  if (tid == 0) {
    float clean[16], sd[16], noisy[16];
#pragma unroll
    for (int e = 0; e < 16; ++e) {
      clean[e] = vals[e];
      float raw = vals[16 + e];
      float sp = fmaxf(raw, 0.f) + log1pf(expf(-fabsf(raw)));
      sd[e] = sp + 0.1f;
      noisy[e] = clean[e] + nz[b * 16 + e] * sd[e];
    }
    float tv[5]; int ti[5]; unsigned used = 0;
    for (int r = 0; r < 5; ++r) {
      float bst = -INFINITY; int bi = 0;
      for (int e = 0; e < 16; ++e)
        if (!((used >> e) & 1u) && noisy[e] > bst) { bst = noisy[e]; bi = e; }
      used |= 1u << bi; tv[r] = bst; ti[r] = bi;
    }
    float gts[4]; float se = 0.f;
#pragma unroll
    for (int k = 0; k < 4; ++k) { gts[k] = expf(tv[k] - tv[0]); se += gts[k]; }
#pragma unroll
    for (int k = 0; k < 4; ++k) gts[k] /= se;
    const float thr_in = tv[4], thr_out = tv[3];
    float imp[16];
#pragma unroll
    for (int e = 0; e < 16; ++e) imp[e] = 0.f;
    for (int k = 0; k < 4; ++k) imp[ti[k]] = gts[k];
    for (int e = 0; e < 16; ++e) imp_part[b * 16 + e] = imp[e];
    for (int e = 0; e < 16; ++e) {
      bool is_in = noisy[e] > thr_in;
      float z = (clean[e] - (is_in ? thr_in : thr_out)) / sd[e];
      load_part[b * 16 + e] = 0.5f * (1.f + erff(z * 0.70710678118654752f));
    }
    for (int k = 0; k < 4; ++k) {
      int ee = ti[k];
      unsigned p = atomicAdd(&cnt[ee], 1u);
      tok_buck[ee * 1024 + (int)p] = b;
      gate_buck[ee * 1024 + (int)p] = gts[k];
    }
  }
}

__device__ __forceinline__ float cv2_16(const float* v) {
  float m = 0.f;
  for (int i = 0; i < 16; ++i) m += v[i];
  m *= (1.f / 16.f);
  float var = 0.f;
  for (int i = 0; i < 16; ++i) { float d = v[i] - m; var += d * d; }
  var *= (1.f / 15.f);
  return var / (m * m + 1e-10f);
}

// ---------------- offsets + loss ----------------
__global__ __launch_bounds__(256) void k_finalize(
    const unsigned* __restrict__ cnt, unsigned* __restrict__ offs,
    const float* __restrict__ imp_part, const float* __restrict__ load_part,
    float* __restrict__ loss_out) {
  const int tid = threadIdx.x;
  __shared__ float red[256];
  __shared__ float impv[16], loadv[16];
  const int e = tid & 15, p = tid >> 4;
  float s = 0.f;
  for (int r = 0; r < 64; ++r) s += imp_part[((p * 64 + r) << 4) + e];
  red[tid] = s;
  __syncthreads();
  if (tid < 16) {
    float t = 0.f;
    for (int pp = 0; pp < 16; ++pp) t += red[pp * 16 + tid];
    impv[tid] = t;
  }
  __syncthreads();
  s = 0.f;
  for (int r = 0; r < 64; ++r) s += load_part[((p * 64 + r) << 4) + e];
  red[tid] = s;
  __syncthreads();
  if (tid < 16) {
    float t = 0.f;
    for (int pp = 0; pp < 16; ++pp) t += red[pp * 16 + tid];
    loadv[tid] = t;
  }
  __syncthreads();
  if (tid == 0) {
    unsigned o = 0;
    for (int ee = 0; ee < 16; ++ee) { offs[ee] = o; o += cnt[ee]; }
    loss_out[0] = (cv2_16(impv) + cv2_16(loadv)) * 1e-4f;
  }
}

// ---------------- GEMM1: h = relu(x @ W1[e] + b1[e]) for routed rows ----------------
// Tile 64m x 128n, 4 waves (1m x 4n), reg-staged double-buffer (R5-verified
// schedule).  Grid 4096 -> ~1024 survivors = 4 blocks/CU (2x TLP vs R5).
__global__ __launch_bounds__(256) void k_gemm1(
    const bh* __restrict__ xbf, const bh* __restrict__ w1t,
    const float* __restrict__ b1, const int* __restrict__ tok_buck,
    const unsigned* __restrict__ cnt, const unsigned* __restrict__ offs,
    bh* __restrict__ hbf) {
  const int lid = blockIdx.x;
  const int xcd = lid & 7, idx = lid >> 3;
  const int mt = idx & 15, g = xcd * 32 + (idx >> 4);
  const int e = g >> 4, nt = g & 15;
  const int ne = (int)cnt[e];
  if (mt * 64 >= ne) return;
  __shared__ __align__(16) bh As[2][64 * 32];    // 4 KB each
  __shared__ __align__(16) bh Bs[2][128 * 32];   // 8 KB each
  const int tid = threadIdx.x;
  const int lane = tid & 63, wv = tid >> 6;

  // A staging: 1 task/thread (64 rows x 4 octets)
  const int arow = tid >> 2, as_ = tid & 3;
  int gm = mt * 64 + arow; if (gm >= ne) gm = ne - 1;
  const int tok = tok_buck[e * 1024 + gm];
  const bh* a_src = xbf + (size_t)tok * 1024 + ((as_ ^ (arow & 3)) << 3);
  const int wA = tid * 16;
  // B staging: 2 tasks/thread (128 rows x 4 octets)
  const bh* b_src0 = w1t + ((size_t)(e * 16 + nt) * 32) * 4096 + (size_t)tid * 8;
  const bh* b_src1 = b_src0 + (size_t)256 * 8;
  const int wB0 = tid * 16, wB1 = (256 + tid) * 16;

  const int ln15 = lane & 15, q = lane >> 4;
  const int qs = ((q ^ (ln15 & 3)) << 3);
  int a_off[4], b_off[2];
#pragma unroll
  for (int i = 0; i < 4; ++i) a_off[i] = (i * 16 + ln15) * 32 + qs;
#pragma unroll
  for (int j = 0; j < 2; ++j) b_off[j] = (wv * 32 + j * 16 + ln15) * 32 + qs;

  fx4 zero = {0.f, 0.f, 0.f, 0.f};
  fx4 acc[4][2];
#pragma unroll
  for (int i = 0; i < 4; ++i)
#pragma unroll
    for (int j = 0; j < 2; ++j) acc[i][j] = zero;

  fx4 sA0, sA1, sB0[2], sB1[2];

#define G1_LOAD(AV, BV, T) do {                               \
    AV = *(const fx4*)(a_src + (T) * 32);                     \
    BV[0] = *(const fx4*)(b_src0 + (size_t)(T) * 4096);       \
    BV[1] = *(const fx4*)(b_src1 + (size_t)(T) * 4096);       \
  } while (0)
#define G1_WRITE(BUF, AV, BV) do {                            \
    *(fx4*)((char*)(&As[BUF][0]) + wA) = AV;                  \
    *(fx4*)((char*)(&Bs[BUF][0]) + wB0) = BV[0];              \
    *(fx4*)((char*)(&Bs[BUF][0]) + wB1) = BV[1];              \
  } while (0)
#define G1_COMPUTE(BUF) do {                                  \
    bh8 af_[4], bf_[2];                                       \
    _Pragma("unroll") for (int i_ = 0; i_ < 4; ++i_)          \
      af_[i_] = *(const bh8*)(&As[BUF][a_off[i_]]);           \
    _Pragma("unroll") for (int j_ = 0; j_ < 2; ++j_)          \
      bf_[j_] = *(const bh8*)(&Bs[BUF][b_off[j_]]);           \
    _Pragma("unroll") for (int i_ = 0; i_ < 4; ++i_)          \
      _Pragma("unroll") for (int j_ = 0; j_ < 2; ++j_)        \
        acc[i_][j_] = __builtin_amdgcn_mfma_f32_16x16x32_bf16(af_[i_], bf_[j_], acc[i_][j_], 0, 0, 0); \
  } while (0)

  G1_LOAD(sA0, sB0, 0);
  for (int t = 0; t < 32; t += 2) {
    __syncthreads();
    G1_LOAD(sA1, sB1, t + 1);
    G1_WRITE(0, sA0, sB0);
    __syncthreads();
    G1_COMPUTE(0);
    __syncthreads();
    if (t + 2 < 32) G1_LOAD(sA0, sB0, t + 2);
    G1_WRITE(1, sA1, sB1);
    __syncthreads();
    G1_COMPUTE(1);
  }

  int nrows = ne - mt * 64; if (nrows > 64) nrows = 64;
  int jn[2]; float b1b[2];
#pragma unroll
  for (int j = 0; j < 2; ++j) {
    jn[j] = nt * 128 + wv * 32 + j * 16 + ln15;
    b1b[j] = b1[e * 2048 + jn[j]];
  }
  const int rowbase = (int)offs[e] + mt * 64;
#pragma unroll
  for (int i = 0; i < 4; ++i)
#pragma unroll
    for (int rr = 0; rr < 4; ++rr) {
      int ml = i * 16 + q * 4 + rr;
      if (ml < nrows) {
        size_t ro = (size_t)(rowbase + ml) * 2048;
#pragma unroll
        for (int j = 0; j < 2; ++j) {
          float vv = acc[i][j][rr] + b1b[j];
          hbf[ro + jn[j]] = (bh)fmaxf(vv, 0.f);
        }
      }
    }
}

// ---------------- GEMM2: y += gate * exp(h @ W2[e] + b2[e]) ----------------
// Tile 64m x 64n, 4 waves (2m x 2n).  Grid 4096 -> ~1024 survivors = 4/CU.
__global__ __launch_bounds__(256) void k_gemm2(
    const bh* __restrict__ hbf, const bh* __restrict__ w2t,
    const float* __restrict__ b2, const int* __restrict__ tok_buck,
    const float* __restrict__ gate_buck, const unsigned* __restrict__ cnt,
    const unsigned* __restrict__ offs, float* __restrict__ yv) {
  const int lid = blockIdx.x;
  const int xcd = lid & 7, idx = lid >> 3;
  const int mt = idx & 15, g = xcd * 32 + (idx >> 4);
  const int e = g >> 4, nt = g & 15;
  const int ne = (int)cnt[e];
  if (mt * 64 >= ne) return;
  __shared__ __align__(16) bh As[2][64 * 32];    // 4 KB each
  __shared__ __align__(16) bh Bs[2][64 * 32];    // 4 KB each
  const int tid = threadIdx.x;
  const int lane = tid & 63, wv = tid >> 6, wm = wv >> 1, wn_ = wv & 1;
  const int rowbase = (int)offs[e] + mt * 64;

  const int arow = tid >> 2, as_ = tid & 3;
  const bh* a_src = hbf + (size_t)(rowbase + arow) * 2048 + ((as_ ^ (arow & 3)) << 3);
  const int wA = tid * 16;
  const bh* b_src = w2t + ((size_t)(e * 16 + nt) * 64) * 2048 + (size_t)tid * 8;
  const int wB = tid * 16;

  const int ln15 = lane & 15, q = lane >> 4;
  const int qs = ((q ^ (ln15 & 3)) << 3);
  int a_off[2], b_off[2];
#pragma unroll
  for (int i = 0; i < 2; ++i) a_off[i] = (wm * 32 + i * 16 + ln15) * 32 + qs;
#pragma unroll
  for (int j = 0; j < 2; ++j) b_off[j] = (wn_ * 32 + j * 16 + ln15) * 32 + qs;

  fx4 zero = {0.f, 0.f, 0.f, 0.f};
  fx4 acc[2][2];
#pragma unroll
  for (int i = 0; i < 2; ++i)
#pragma unroll
    for (int j = 0; j < 2; ++j) acc[i][j] = zero;

  fx4 sA0, sA1, sB0, sB1;

#define G2_LOAD(AV, BV, T) do {                               \
    AV = *(const fx4*)(a_src + (T) * 32);                     \
    BV = *(const fx4*)(b_src + (size_t)(T) * 2048);           \
  } while (0)
#define G2_WRITE(BUF, AV, BV) do {                            \
    *(fx4*)((char*)(&As[BUF][0]) + wA) = AV;                  \
    *(fx4*)((char*)(&Bs[BUF][0]) + wB) = BV;                  \
  } while (0)
#define G2_COMPUTE(BUF) do {                                  \
    bh8 af_[2], bf_[2];                                       \
    _Pragma("unroll") for (int i_ = 0; i_ < 2; ++i_)          \
      af_[i_] = *(const bh8*)(&As[BUF][a_off[i_]]);           \
    _Pragma("unroll") for (int j_ = 0; j_ < 2; ++j_)          \
      bf_[j_] = *(const bh8*)(&Bs[BUF][b_off[j_]]);           \
    _Pragma("unroll") for (int i_ = 0; i_ < 2; ++i_)          \
      _Pragma("unroll") for (int j_ = 0; j_ < 2; ++j_)        \
        acc[i_][j_] = __builtin_amdgcn_mfma_f32_16x16x32_bf16(af_[i_], bf_[j_], acc[i_][j_], 0, 0, 0); \
  } while (0)

  G2_LOAD(sA0, sB0, 0);
  for (int t = 0; t < 64; t += 2) {
    __syncthreads();
    G2_LOAD(sA1, sB1, t + 1);
    G2_WRITE(0, sA0, sB0);
    __syncthreads();
    G2_COMPUTE(0);
    __syncthreads();
    if (t + 2 < 64) G2_LOAD(sA0, sB0, t + 2);
    G2_WRITE(1, sA1, sB1);
    __syncthreads();
    G2_COMPUTE(1);
  }

  int nrows = ne - mt * 64; if (nrows > 64) nrows = 64;
  int on[2]; float b2v[2];
#pragma unroll
  for (int j = 0; j < 2; ++j) {
    on[j] = nt * 64 + wn_ * 32 + j * 16 + ln15;
    b2v[j] = b2[e * 1024 + on[j]];
  }
#pragma unroll
  for (int i = 0; i < 2; ++i)
#pragma unroll
    for (int rr = 0; rr < 4; ++rr) {
      int ml = wm * 32 + i * 16 + q * 4 + rr;
      if (ml < nrows) {
        int pos = mt * 64 + ml;
        int bt = tok_buck[e * 1024 + pos];
        float gg = gate_buck[e * 1024 + pos];
        float* yrow = yv + (size_t)bt * 1024;
#pragma unroll
        for (int j = 0; j < 2; ++j)
          atomicAdd(&yrow[on[j]], gg * expf(acc[i][j][rr] + b2v[j]));
      }
    }
}

// ---------------- final log ----------------
__global__ __launch_bounds__(256) void k_log(float* __restrict__ yv) {
  const int i = blockIdx.x * 256 + threadIdx.x;
  fx4* p = (fx4*)yv + i;
  fx4 v = *p;
#pragma unroll
  for (int c = 0; c < 4; ++c) {
    float w = v[c];
    if (w == 0.f) w = 2.2204460492503131e-16f;
    v[c] = logf(w);
  }
  *p = v;
}

extern "C" void kernel_launch(void* const* d_in, const int* in_sizes, int n_in,
                              void* d_out, int out_size, void* d_ws, size_t ws_size,
                              hipStream_t stream) {
  const float* x  = (const float*)d_in[0];
  const float* wg = (const float*)d_in[1];
  const float* wn = (const float*)d_in[2];
  const float* W1 = (const float*)d_in[3];
  const float* b1 = (const float*)d_in[4];
  const float* W2 = (const float*)d_in[5];
  const float* b2 = (const float*)d_in[6];
  const float* nz = (const float*)d_in[7];
  float* out = (float*)d_out;

  // workspace layout (bytes)
  char* ws = (char*)d_ws;
  unsigned* cnt      = (unsigned*)(ws + 0);          // 64 B
  unsigned* offs     = (unsigned*)(ws + 64);         // 64 B
  float*    imp_part = (float*)(ws + 256);           // 64 KB
  float*    load_part= (float*)(ws + 256 + 65536);   // 64 KB
  int*      tok_buck = (int*)(ws + 256 + 2 * 65536); // 64 KB
  float*    gate_buck= (float*)(ws + 256 + 3 * 65536); // 64 KB
  bh*       xbf      = (bh*)(ws + 262400);           // 2 MB
  bh*       hbf      = (bh*)(ws + 2359552);          // (4096+128)*2048*2 = 16.5 MiB
  bh*       w1t      = (bh*)(ws + 19661056);         // 64 MiB (tiled, 128-wide panels)
  bh*       w2t      = (bh*)(ws + 86769920);         // 64 MiB (tiled, 64-wide panels)
  const size_t needed = 153878784;
  if (ws_size < needed) {
    // sentinel: distinguishable failure mode (absmax ~48) if ws is too small
    hipMemsetAsync(d_out, 0x42, (size_t)out_size * 4, stream);
    return;
  }

  hipMemsetAsync(d_out, 0, (size_t)out_size * 4, stream);
  hipMemsetAsync(cnt, 0, 64, stream);

  // W1 [e][1024][2048]: K=1024 (KT=32), N=2048, panels of 128 (NT=16)
  k_tcvt2<<<dim3(32, 16, 16), 256, 0, stream>>>(W1, w1t, 1024, 2048, 32, 16, 128, 5);
  // W2 [e][2048][1024]: K=2048 (KT=64), N=1024, panels of 64 (NT=16)
  k_tcvt2<<<dim3(64, 16, 16), 256, 0, stream>>>(W2, w2t, 2048, 1024, 64, 16, 64, 4);
  k_gating<<<1024, 256, 0, stream>>>(x, wg, wn, nz, xbf, cnt, tok_buck, gate_buck,
                                     imp_part, load_part);
  k_finalize<<<1, 256, 0, stream>>>(cnt, offs, imp_part, load_part, out + (out_size - 1));
  k_gemm1<<<4096, 256, 0, stream>>>(xbf, w1t, b1, tok_buck, cnt, offs, hbf);
  k_gemm2<<<4096, 256, 0, stream>>>(hbf, w2t, b2, tok_buck, gate_buck, cnt, offs, out);
  k_log<<<1024, 256, 0, stream>>>(out);
}